// Round 12
// baseline (185.258 us; speedup 1.0000x reference)
//
#include <hip/hip_runtime.h>
#include <cstdint>
#include <cstddef>

#define B_ 2
#define N_ 2048
#define C_ 256
#define H_ 64
#define W_ 176
#define TW 16
#define NTX 11                    // 176/16 tiles per row
#define NYB 32                    // 2-row bands
#define NTILES2 (B_*NYB*NTX)      // 704 tiles (16px x 2row)
#define CAP 1024                  // per-tile list cap (est max ~200)
#define SA 260                    // mlp act LDS stride (floats)

typedef unsigned short ushort_t;
typedef short bf16x8 __attribute__((ext_vector_type(8)));
typedef float f32x4  __attribute__((ext_vector_type(4)));

__device__ __forceinline__ short f2bf(float f)   // RNE fp32->bf16
{
    unsigned u = __float_as_uint(f);
    return (short)((u + 0x7FFFu + ((u >> 16) & 1u)) >> 16);
}

// global->LDS direct DMA: each lane moves 16B; dest = uniform base + lane*16.
__device__ __forceinline__ void gl_lds16u(const ushort_t* gsrc, ushort_t* ldst)
{
    auto gp = (const __attribute__((address_space(1))) unsigned int*)(uintptr_t)gsrc;
    auto lp = (__attribute__((address_space(3))) unsigned int*)(unsigned int)(uintptr_t)ldst;
    __builtin_amdgcn_global_load_lds(gp, lp, 16, 0, 0);
}

// ---------------------------------------------------------------------------
// prep: zero tile counters + fp32->bf16 transposed weight convert (coalesced
// writes). grid 256 x 256.
// ---------------------------------------------------------------------------
__global__ __launch_bounds__(256)
void prep_kernel(const float* __restrict__ w3f, const float* __restrict__ fw1f,
                 const float* __restrict__ fw2f,
                 short* __restrict__ wt3, short* __restrict__ wt4,
                 short* __restrict__ wt5, int* __restrict__ counts)
{
    const int gid = blockIdx.x * 256 + threadIdx.x;
    if (gid < NTILES2) counts[gid] = 0;
    for (int e = gid; e < 163840; e += 65536) {
        if (e < 32768) {
            const int i = e;
            wt3[i] = f2bf(w3f[(i & 127) * 256 + (i >> 7)]);
        } else if (e < 98304) {
            const int i = e - 32768;
            wt4[i] = f2bf(fw1f[(i & 255) * 256 + (i >> 8)]);
        } else {
            const int i = e - 98304;
            wt5[i] = f2bf(fw2f[(i & 255) * 256 + (i >> 8)]);
        }
    }
}

// ---------------------------------------------------------------------------
// MFMA accumulate, 8-wave version: wave wv_ covers cols (wv_*2+tt)*16, tt<2.
// ---------------------------------------------------------------------------
template<int K>
__device__ __forceinline__ void mfma_acc(const short* __restrict__ wt,
                                         const float* actIn, f32x4 (&acc)[2],
                                         int wv_, int quad, int ln15)
{
#pragma unroll
    for (int ks = 0; ks < K / 32; ++ks) {
        const int kb = ks * 32 + quad * 8;
        const float4 a0 = *(const float4*)&actIn[ln15 * SA + kb];
        const float4 a1 = *(const float4*)&actIn[ln15 * SA + kb + 4];
        bf16x8 af = { f2bf(a0.x), f2bf(a0.y), f2bf(a0.z), f2bf(a0.w),
                      f2bf(a1.x), f2bf(a1.y), f2bf(a1.z), f2bf(a1.w) };
#pragma unroll
        for (int tt = 0; tt < 2; ++tt) {
            const int n0 = (wv_ * 2 + tt) * 16;
            const bf16x8 bf = *(const bf16x8*)&wt[(size_t)(n0 + ln15) * K + kb];
            acc[tt] = __builtin_amdgcn_mfma_f32_16x16x32_bf16(af, bf, acc[tt], 0, 0, 0);
        }
    }
}

// ---------------------------------------------------------------------------
// Fused MLP + param/bin, 512 threads:
//   blocks 0..255   : MLP, 16 rows each, 8 waves split over N (latency hiding)
//   blocks 256..511 : param+bin, 16 gaussians x 32 y-band candidates
// ---------------------------------------------------------------------------
__global__ __launch_bounds__(512)
void pb_mlp_kernel(const float* __restrict__ g, const float* __restrict__ intr,
                   const float* __restrict__ w1, const float* __restrict__ b1,
                   const float* __restrict__ w2, const float* __restrict__ b2,
                   const short* __restrict__ wt3, const float* __restrict__ b3,
                   const short* __restrict__ wt4, const float* __restrict__ fb1,
                   const short* __restrict__ wt5, const float* __restrict__ fb2,
                   ushort_t* __restrict__ ftb,
                   float* __restrict__ pp, int* __restrict__ counts,
                   ushort_t* __restrict__ lists)
{
    __shared__ __align__(16) float A_[16 * SA];
    __shared__ __align__(16) float Bb[16 * SA];
    const int tid = threadIdx.x;

    if (blockIdx.x < 256) {
        // ================= MLP role =================
        const int row0 = blockIdx.x * 16;
        const int lane = tid & 63;
        const int wv_  = tid >> 6;        // 0..7
        const int quad = lane >> 4;
        const int ln15 = lane & 15;

        if (tid < 224) {
            const int k = tid / 16, m = tid % 16;
            A_[m * SA + k] = g[(size_t)(row0 + m) * 14 + k];
        }
        __syncthreads();

        {   // L1: 14 -> 64, relu. thread = col(64) x 2 rows
            const int col = tid & 63;
            const int m0  = (tid >> 6) * 2;
            float acc[2];
            const float bv = b1[col];
            acc[0] = bv; acc[1] = bv;
#pragma unroll
            for (int k = 0; k < 14; ++k) {
                const float wv = w1[k * 64 + col];
                acc[0] = fmaf(A_[(m0 + 0) * SA + k], wv, acc[0]);
                acc[1] = fmaf(A_[(m0 + 1) * SA + k], wv, acc[1]);
            }
            Bb[(m0 + 0) * SA + col] = fmaxf(acc[0], 0.f);
            Bb[(m0 + 1) * SA + col] = fmaxf(acc[1], 0.f);
        }
        __syncthreads();

        {   // L2: 64 -> 128, relu. thread = col(128) x 4 rows
            const int col = tid & 127;
            const int m0  = (tid >> 7) * 4;
            float acc[4];
            const float bv = b2[col];
#pragma unroll
            for (int r = 0; r < 4; ++r) acc[r] = bv;
#pragma unroll 4
            for (int kq = 0; kq < 16; ++kq) {
                float wv[4];
#pragma unroll
                for (int jj = 0; jj < 4; ++jj) wv[jj] = w2[(4 * kq + jj) * 128 + col];
#pragma unroll
                for (int r = 0; r < 4; ++r) {
                    const float4 a4 = *(const float4*)&Bb[(m0 + r) * SA + 4 * kq];
                    acc[r] = fmaf(a4.x, wv[0], acc[r]);
                    acc[r] = fmaf(a4.y, wv[1], acc[r]);
                    acc[r] = fmaf(a4.z, wv[2], acc[r]);
                    acc[r] = fmaf(a4.w, wv[3], acc[r]);
                }
            }
#pragma unroll
            for (int r = 0; r < 4; ++r)
                A_[(m0 + r) * SA + col] = fmaxf(acc[r], 0.f);
        }
        __syncthreads();

        {   // L3: 128 -> 256 MFMA
            f32x4 acc[2] = {{0,0,0,0},{0,0,0,0}};
            mfma_acc<128>(wt3, A_, acc, wv_, quad, ln15);
            __syncthreads();
#pragma unroll
            for (int tt = 0; tt < 2; ++tt) {
                const int n = (wv_ * 2 + tt) * 16 + ln15;
                const float bv = b3[n];
#pragma unroll
                for (int r = 0; r < 4; ++r)
                    Bb[(quad * 4 + r) * SA + n] = acc[tt][r] + bv;
            }
        }
        __syncthreads();

        {   // L4: 256 -> 256 MFMA, relu
            f32x4 acc[2] = {{0,0,0,0},{0,0,0,0}};
            mfma_acc<256>(wt4, Bb, acc, wv_, quad, ln15);
            __syncthreads();
#pragma unroll
            for (int tt = 0; tt < 2; ++tt) {
                const int n = (wv_ * 2 + tt) * 16 + ln15;
                const float bv = fb1[n];
#pragma unroll
                for (int r = 0; r < 4; ++r)
                    A_[(quad * 4 + r) * SA + n] = fmaxf(acc[tt][r] + bv, 0.f);
            }
        }
        __syncthreads();

        {   // L5: 256 -> 256 MFMA -> global bf16
            f32x4 acc[2] = {{0,0,0,0},{0,0,0,0}};
            mfma_acc<256>(wt5, A_, acc, wv_, quad, ln15);
#pragma unroll
            for (int tt = 0; tt < 2; ++tt) {
                const int n = (wv_ * 2 + tt) * 16 + ln15;
                const float bv = fb2[n];
#pragma unroll
                for (int r = 0; r < 4; ++r)
                    ftb[(size_t)(row0 + quad * 4 + r) * 256 + n] =
                        (ushort_t)f2bf(acc[tt][r] + bv);
            }
        }
        return;
    }

    // ================= param + bin role (2-row bands) =================
    const int i = (blockIdx.x - 256) * 16 + (tid >> 5);
    const int j = tid & 31;
    const float* gi = g + (size_t)i * 14;
    const float x = gi[0], y = gi[1], z = gi[2];
    const float s5 = gi[5], s6 = gi[6], wv = gi[12];
    const float k00 = intr[0], k01 = intr[1], k02 = intr[2];
    const float k10 = intr[3], k11 = intr[4], k12 = intr[5];
    const float k20 = intr[6], k21 = intr[7], k22 = intr[8];
    const float projx = k00 * x + k01 * y + k02 * z;
    const float projy = k10 * x + k11 * y + k12 * z;
    const float projz = k20 * x + k21 * y + k22 * z;
    const float inv = 1.f / (projz + 1e-6f);
    const float scale_x = (float)W_ / k02 * 0.5f;
    const float scale_y = (float)H_ / k12 * 0.5f;
    const float px = projx * inv * scale_x;
    const float py = projy * inv * scale_y;
    const bool valid = z > 0.1f;
    const bool inb = (px >= 0.f) && (px < (float)W_) && (py >= 0.f) && (py < (float)H_);
    const bool mask = valid && inb;
    const float sx = fmaxf(s5 * scale_x, 1.f);
    const float sy = fmaxf(s6 * scale_y, 1.f);
    if (j == 0) {
        float4* o = (float4*)(pp + (size_t)i * 8);
        o[0] = make_float4(px, py, 1.f / sx, 1.f / sy);
        o[1] = make_float4(wv, 0.5f * (sx + sy), 0.f, 0.f);
    }
    if (!mask) return;
    const float rx = 3.f * sx, ry = 3.f * sy;
    const int ymin = max(0, (int)floorf(py - ry));
    const int ymax = min(H_ - 1, (int)ceilf(py + ry));
    const int bmin = ymin >> 1, bmax = ymax >> 1;
    const int band = bmin + j;
    if (band > bmax) return;
    const int tmin = max(0, (int)floorf((px - rx - (float)(TW - 1)) * (1.f / TW)));
    const int tmax = min(NTX - 1, (int)ceilf((px + rx) * (1.f / TW)));
    const int b = i / N_, n = i - b * N_;
    for (int t = tmin; t <= tmax; ++t) {
        const int tile = (b * NYB + band) * NTX + t;
        const int slot = atomicAdd(&counts[tile], 1);
        if (slot < CAP) lists[(size_t)tile * CAP + slot] = (ushort_t)n;
    }
}

// ---------------------------------------------------------------------------
// Splat: block = 16px x 2row tile (704 blocks, ALL co-resident at 3/CU).
// Chunks of 32 gaussians, double-buffered bf16 feats via global_load_lds.
// Phase A: thread (gs 0..7, px32 0..31) computes 4 gw per chunk.
// Phase B: thread (cho 0..31, ppb 0..7) = 8ch x 4px; per q: 1 uint4 feats +
// 1 float4 gws -> 32 FMA. No parity merge.
// ---------------------------------------------------------------------------
__global__ __launch_bounds__(256)
void splat_kernel(const float* __restrict__ pp, const ushort_t* __restrict__ lists,
                  const int* __restrict__ counts, const ushort_t* __restrict__ feats,
                  float* __restrict__ out)
{
    __shared__ __align__(16) ushort_t feats_bf[2][32 * C_];  // 2 x 16 KB
    __shared__ __align__(16) float gws[2][32 * 36];          // 2 x 4.5 KB

    const int tid = threadIdx.x;
    // center-first tile decode
    const int qb = blockIdx.x;
    const int b  = qb & 1;
    const int t_ = qb >> 1;
    const int yr = t_ / NTX, xr = t_ % NTX;
    const int yh = (yr + 1) >> 1;
    const int yb = (yr & 1) ? (16 - yh) : (16 + yh);
    const int xh = (xr + 1) >> 1;
    const int txi = (xr & 1) ? (5 - xh) : (5 + xh);
    const int bid = (b * NYB + yb) * NTX + txi;
    const int y0 = yb * 2, x0 = txi * TW;

    const int cnt = min(counts[bid], CAP);
    const ushort_t* mylist = lists + (size_t)bid * CAP;
    const int gs   = tid >> 5;            // phase A gaussian sub-slot (0..7)
    const int px32 = tid & 31;            // phase A pixel (row*16+px)
    const float fy = (float)(y0 + (px32 >> 4));
    const float fx = (float)(x0 + (px32 & 15));
    const int cho = tid >> 3;             // phase B ch octet (0..31)
    const int ppb = tid & 7;              // phase B px quad: row*4+quad
    const int brow = ppb >> 2, bquad = ppb & 3;
    const int bN = b * N_;
    const int lane = tid & 63;
    const int wid  = tid >> 6;

    float acc[8][4];
#pragma unroll
    for (int cc = 0; cc < 8; ++cc)
#pragma unroll
        for (int k = 0; k < 4; ++k) acc[cc][k] = 0.f;
    float densp = 0.f, uncp = 0.f;

    if (cnt > 0) {
        const float4* pv = (const float4*)pp;
        // prologue DMA chunk 0: wave wid stages rows 8wid..8wid+7 (2/instr)
        {
            const int idx = mylist[min(8 * wid + (lane & 7), cnt - 1)];
#pragma unroll
            for (int jj = 0; jj < 4; ++jj) {
                const int nLo = __shfl(idx, 2 * jj);
                const int nHi = __shfl(idx, 2 * jj + 1);
                const int n = (lane < 32) ? nLo : nHi;
                gl_lds16u(feats + ((size_t)(bN + n) << 8) + (lane & 31) * 8,
                          &feats_bf[0][(8 * wid + 2 * jj) * 256] + lane * 8);
            }
        }
        const int nchunks = (cnt + 31) >> 5;
        for (int c = 0; c < nchunks; ++c) {
            const int buf = c & 1;
            // phase A: 4 gaussians per thread
#pragma unroll
            for (int jj = 0; jj < 4; ++jj) {
                const int q = 8 * jj + gs;
                const int qi = c * 32 + q;
                const int n = mylist[min(qi, cnt - 1)];
                const float4 e0 = pv[(size_t)(bN + n) * 2 + 0];
                const float4 e1 = pv[(size_t)(bN + n) * 2 + 1];
                const float dyn = (fy - e0.y) * e0.w;
                const float dxn = (fx - e0.x) * e0.z;
                const float dist = dyn * dyn + dxn * dxn;
                float gv = 0.f;
                if (dist < 9.f) gv = __expf(-0.5f * dist) * e1.x;
                if (qi >= cnt) gv = 0.f;
                gws[buf][q * 36 + px32] = gv;
                densp += gv;
                uncp  += gv * e1.y;
            }
            __syncthreads();              // gws/feats[buf] ready (drains DMA)
            if (c + 1 < nchunks) {        // DMA chunk c+1 (overlaps phase B)
                const int idx = mylist[min((c + 1) * 32 + 8 * wid + (lane & 7), cnt - 1)];
#pragma unroll
                for (int jj = 0; jj < 4; ++jj) {
                    const int nLo = __shfl(idx, 2 * jj);
                    const int nHi = __shfl(idx, 2 * jj + 1);
                    const int n = (lane < 32) ? nLo : nHi;
                    gl_lds16u(feats + ((size_t)(bN + n) << 8) + (lane & 31) * 8,
                              &feats_bf[buf ^ 1][(8 * wid + 2 * jj) * 256] + lane * 8);
                }
            }
            // phase B: 32 q, 8ch x 4px per thread
#pragma unroll 4
            for (int q = 0; q < 32; ++q) {
                const uint4 fw = *(const uint4*)&feats_bf[buf][q * 256 + cho * 8];
                const float4 g4 = *(const float4*)&gws[buf][q * 36 + brow * 16 + bquad * 4];
                float fch[8];
                fch[0] = __uint_as_float(fw.x << 16);
                fch[1] = __uint_as_float(fw.x & 0xffff0000u);
                fch[2] = __uint_as_float(fw.y << 16);
                fch[3] = __uint_as_float(fw.y & 0xffff0000u);
                fch[4] = __uint_as_float(fw.z << 16);
                fch[5] = __uint_as_float(fw.z & 0xffff0000u);
                fch[6] = __uint_as_float(fw.w << 16);
                fch[7] = __uint_as_float(fw.w & 0xffff0000u);
#pragma unroll
                for (int cc = 0; cc < 8; ++cc) {
                    acc[cc][0] = fmaf(fch[cc], g4.x, acc[cc][0]);
                    acc[cc][1] = fmaf(fch[cc], g4.y, acc[cc][1]);
                    acc[cc][2] = fmaf(fch[cc], g4.z, acc[cc][2]);
                    acc[cc][3] = fmaf(fch[cc], g4.w, acc[cc][3]);
                }
            }
        }
    }

    // density / uncertainty reduction over 8 gs-groups (scratch in feats_bf)
    __syncthreads();
    float* red_d = (float*)&feats_bf[0][0];   // 8 x 36
    float* red_u = red_d + 8 * 36;
    red_d[gs * 36 + px32] = densp;
    red_u[gs * 36 + px32] = uncp;
    __syncthreads();
    for (int s = 4; s > 0; s >>= 1) {
        if (gs < s) {
            red_d[gs * 36 + px32] += red_d[(gs + s) * 36 + px32];
            red_u[gs * 36 + px32] += red_u[(gs + s) * 36 + px32];
        }
        __syncthreads();
    }

    float rinv[4];
#pragma unroll
    for (int k = 0; k < 4; ++k)
        rinv[k] = 1.f / fmaxf(red_d[brow * 16 + bquad * 4 + k], 1e-6f);
    if (tid < 32) {
        const int yy = y0 + (tid >> 4), xx = x0 + (tid & 15);
        const size_t pix = ((size_t)b * H_ + yy) * W_ + xx;
        float* unc_o = out + (size_t)B_ * C_ * H_ * W_;
        float* den_o = unc_o + (size_t)B_ * H_ * W_;
        const float d = fmaxf(red_d[tid], 1e-6f);
        unc_o[pix] = red_u[tid] / d;
        den_o[pix] = d;
    }

#pragma unroll
    for (int cc = 0; cc < 8; ++cc) {
        const int ch = cho * 8 + cc;
        float4 v;
        v.x = acc[cc][0] * rinv[0];
        v.y = acc[cc][1] * rinv[1];
        v.z = acc[cc][2] * rinv[2];
        v.w = acc[cc][3] * rinv[3];
        *(float4*)(out + (((size_t)b * C_ + ch) * H_ + y0 + brow) * W_
                   + x0 + bquad * 4) = v;
    }
}

// ---------------------------------------------------------------------------
extern "C" void kernel_launch(void* const* d_in, const int* in_sizes, int n_in,
                              void* d_out, int out_size, void* d_ws, size_t ws_size,
                              hipStream_t stream)
{
    const float* g    = (const float*)d_in[0];
    const float* intr = (const float*)d_in[1];
    const float* w1   = (const float*)d_in[2];
    const float* b1   = (const float*)d_in[3];
    const float* w2   = (const float*)d_in[4];
    const float* b2   = (const float*)d_in[5];
    const float* w3   = (const float*)d_in[6];
    const float* b3   = (const float*)d_in[7];
    const float* fw1  = (const float*)d_in[8];
    const float* fb1  = (const float*)d_in[9];
    const float* fw2  = (const float*)d_in[10];
    const float* fb2  = (const float*)d_in[11];

    char* base = (char*)d_ws;
    const int rows = B_ * N_;                                // 4096
    ushort_t* ftb = (ushort_t*)base;                         // 2 MB bf16 [row][ch]
    float* pp     = (float*)(base + (size_t)rows * C_ * 2);  // 128 KB
    int*   counts = (int*)(pp + (size_t)8 * rows);           // 704 ints
    ushort_t* lists = (ushort_t*)(counts + NTILES2);         // 704*1024*2B = 1.4 MB
    short* wt3    = (short*)(lists + (size_t)NTILES2 * CAP);
    short* wt4    = wt3 + 128 * 256;
    short* wt5    = wt4 + 256 * 256;

    prep_kernel<<<dim3(256), dim3(256), 0, stream>>>(w3, fw1, fw2, wt3, wt4, wt5, counts);
    pb_mlp_kernel<<<dim3(512), dim3(512), 0, stream>>>(
        g, intr, w1, b1, w2, b2, wt3, b3, wt4, fb1, wt5, fb2, ftb, pp, counts, lists);
    splat_kernel<<<dim3(NTILES2), dim3(256), 0, stream>>>(pp, lists, counts, ftb, (float*)d_out);
}

// Round 13
// 165.865 us; speedup vs baseline: 1.1169x; 1.1169x over previous
//
#include <hip/hip_runtime.h>
#include <cstdint>
#include <cstddef>

#define B_ 2
#define N_ 2048
#define C_ 256
#define H_ 64
#define W_ 176
#define TW 16
#define NTX 11                    // 176/16 tiles per row
#define NYB 32                    // 2-row bands
#define NTILES2 (B_*NYB*NTX)      // 704 tiles (16px x 2row)
#define CAP 1024                  // per-tile list cap
#define SA 260                    // mlp act LDS stride (floats)
#define FS 40                     // feats_t / gw_t row stride (ushort) = 80 B

typedef unsigned short ushort_t;
typedef short bf16x8 __attribute__((ext_vector_type(8)));
typedef float f32x4  __attribute__((ext_vector_type(4)));

__device__ __forceinline__ short f2bf(float f)   // RNE fp32->bf16
{
    unsigned u = __float_as_uint(f);
    return (short)((u + 0x7FFFu + ((u >> 16) & 1u)) >> 16);
}

// ---------------------------------------------------------------------------
// prep: zero tile counters + fp32->bf16 transposed weight convert (coalesced
// writes). grid 256 x 256.
// ---------------------------------------------------------------------------
__global__ __launch_bounds__(256)
void prep_kernel(const float* __restrict__ w3f, const float* __restrict__ fw1f,
                 const float* __restrict__ fw2f,
                 short* __restrict__ wt3, short* __restrict__ wt4,
                 short* __restrict__ wt5, int* __restrict__ counts)
{
    const int gid = blockIdx.x * 256 + threadIdx.x;
    if (gid < NTILES2) counts[gid] = 0;
    for (int e = gid; e < 163840; e += 65536) {
        if (e < 32768) {
            const int i = e;
            wt3[i] = f2bf(w3f[(i & 127) * 256 + (i >> 7)]);
        } else if (e < 98304) {
            const int i = e - 32768;
            wt4[i] = f2bf(fw1f[(i & 255) * 256 + (i >> 8)]);
        } else {
            const int i = e - 98304;
            wt5[i] = f2bf(fw2f[(i & 255) * 256 + (i >> 8)]);
        }
    }
}

// ---------------------------------------------------------------------------
// MFMA accumulate, 8-wave MLP version.
// ---------------------------------------------------------------------------
template<int K>
__device__ __forceinline__ void mfma_acc(const short* __restrict__ wt,
                                         const float* actIn, f32x4 (&acc)[2],
                                         int wv_, int quad, int ln15)
{
#pragma unroll
    for (int ks = 0; ks < K / 32; ++ks) {
        const int kb = ks * 32 + quad * 8;
        const float4 a0 = *(const float4*)&actIn[ln15 * SA + kb];
        const float4 a1 = *(const float4*)&actIn[ln15 * SA + kb + 4];
        bf16x8 af = { f2bf(a0.x), f2bf(a0.y), f2bf(a0.z), f2bf(a0.w),
                      f2bf(a1.x), f2bf(a1.y), f2bf(a1.z), f2bf(a1.w) };
#pragma unroll
        for (int tt = 0; tt < 2; ++tt) {
            const int n0 = (wv_ * 2 + tt) * 16;
            const bf16x8 bf = *(const bf16x8*)&wt[(size_t)(n0 + ln15) * K + kb];
            acc[tt] = __builtin_amdgcn_mfma_f32_16x16x32_bf16(af, bf, acc[tt], 0, 0, 0);
        }
    }
}

// ---------------------------------------------------------------------------
// Fused MLP + param/bin, 512 threads (R12, unchanged).
// ---------------------------------------------------------------------------
__global__ __launch_bounds__(512)
void pb_mlp_kernel(const float* __restrict__ g, const float* __restrict__ intr,
                   const float* __restrict__ w1, const float* __restrict__ b1,
                   const float* __restrict__ w2, const float* __restrict__ b2,
                   const short* __restrict__ wt3, const float* __restrict__ b3,
                   const short* __restrict__ wt4, const float* __restrict__ fb1,
                   const short* __restrict__ wt5, const float* __restrict__ fb2,
                   ushort_t* __restrict__ ftb,
                   float* __restrict__ pp, int* __restrict__ counts,
                   ushort_t* __restrict__ lists)
{
    __shared__ __align__(16) float A_[16 * SA];
    __shared__ __align__(16) float Bb[16 * SA];
    const int tid = threadIdx.x;

    if (blockIdx.x < 256) {
        const int row0 = blockIdx.x * 16;
        const int lane = tid & 63;
        const int wv_  = tid >> 6;
        const int quad = lane >> 4;
        const int ln15 = lane & 15;

        if (tid < 224) {
            const int k = tid / 16, m = tid % 16;
            A_[m * SA + k] = g[(size_t)(row0 + m) * 14 + k];
        }
        __syncthreads();

        {   // L1: 14 -> 64, relu
            const int col = tid & 63;
            const int m0  = (tid >> 6) * 2;
            float acc[2];
            const float bv = b1[col];
            acc[0] = bv; acc[1] = bv;
#pragma unroll
            for (int k = 0; k < 14; ++k) {
                const float wv = w1[k * 64 + col];
                acc[0] = fmaf(A_[(m0 + 0) * SA + k], wv, acc[0]);
                acc[1] = fmaf(A_[(m0 + 1) * SA + k], wv, acc[1]);
            }
            Bb[(m0 + 0) * SA + col] = fmaxf(acc[0], 0.f);
            Bb[(m0 + 1) * SA + col] = fmaxf(acc[1], 0.f);
        }
        __syncthreads();

        {   // L2: 64 -> 128, relu
            const int col = tid & 127;
            const int m0  = (tid >> 7) * 4;
            float acc[4];
            const float bv = b2[col];
#pragma unroll
            for (int r = 0; r < 4; ++r) acc[r] = bv;
#pragma unroll 4
            for (int kq = 0; kq < 16; ++kq) {
                float wv[4];
#pragma unroll
                for (int jj = 0; jj < 4; ++jj) wv[jj] = w2[(4 * kq + jj) * 128 + col];
#pragma unroll
                for (int r = 0; r < 4; ++r) {
                    const float4 a4 = *(const float4*)&Bb[(m0 + r) * SA + 4 * kq];
                    acc[r] = fmaf(a4.x, wv[0], acc[r]);
                    acc[r] = fmaf(a4.y, wv[1], acc[r]);
                    acc[r] = fmaf(a4.z, wv[2], acc[r]);
                    acc[r] = fmaf(a4.w, wv[3], acc[r]);
                }
            }
#pragma unroll
            for (int r = 0; r < 4; ++r)
                A_[(m0 + r) * SA + col] = fmaxf(acc[r], 0.f);
        }
        __syncthreads();

        {   // L3: 128 -> 256 MFMA
            f32x4 acc[2] = {{0,0,0,0},{0,0,0,0}};
            mfma_acc<128>(wt3, A_, acc, wv_, quad, ln15);
            __syncthreads();
#pragma unroll
            for (int tt = 0; tt < 2; ++tt) {
                const int n = (wv_ * 2 + tt) * 16 + ln15;
                const float bv = b3[n];
#pragma unroll
                for (int r = 0; r < 4; ++r)
                    Bb[(quad * 4 + r) * SA + n] = acc[tt][r] + bv;
            }
        }
        __syncthreads();

        {   // L4: 256 -> 256 MFMA, relu
            f32x4 acc[2] = {{0,0,0,0},{0,0,0,0}};
            mfma_acc<256>(wt4, Bb, acc, wv_, quad, ln15);
            __syncthreads();
#pragma unroll
            for (int tt = 0; tt < 2; ++tt) {
                const int n = (wv_ * 2 + tt) * 16 + ln15;
                const float bv = fb1[n];
#pragma unroll
                for (int r = 0; r < 4; ++r)
                    A_[(quad * 4 + r) * SA + n] = fmaxf(acc[tt][r] + bv, 0.f);
            }
        }
        __syncthreads();

        {   // L5: 256 -> 256 MFMA -> global bf16
            f32x4 acc[2] = {{0,0,0,0},{0,0,0,0}};
            mfma_acc<256>(wt5, A_, acc, wv_, quad, ln15);
#pragma unroll
            for (int tt = 0; tt < 2; ++tt) {
                const int n = (wv_ * 2 + tt) * 16 + ln15;
                const float bv = fb2[n];
#pragma unroll
                for (int r = 0; r < 4; ++r)
                    ftb[(size_t)(row0 + quad * 4 + r) * 256 + n] =
                        (ushort_t)f2bf(acc[tt][r] + bv);
            }
        }
        return;
    }

    // ================= param + bin role (2-row bands) =================
    const int i = (blockIdx.x - 256) * 16 + (tid >> 5);
    const int j = tid & 31;
    const float* gi = g + (size_t)i * 14;
    const float x = gi[0], y = gi[1], z = gi[2];
    const float s5 = gi[5], s6 = gi[6], wv = gi[12];
    const float k00 = intr[0], k01 = intr[1], k02 = intr[2];
    const float k10 = intr[3], k11 = intr[4], k12 = intr[5];
    const float k20 = intr[6], k21 = intr[7], k22 = intr[8];
    const float projx = k00 * x + k01 * y + k02 * z;
    const float projy = k10 * x + k11 * y + k12 * z;
    const float projz = k20 * x + k21 * y + k22 * z;
    const float inv = 1.f / (projz + 1e-6f);
    const float scale_x = (float)W_ / k02 * 0.5f;
    const float scale_y = (float)H_ / k12 * 0.5f;
    const float px = projx * inv * scale_x;
    const float py = projy * inv * scale_y;
    const bool valid = z > 0.1f;
    const bool inb = (px >= 0.f) && (px < (float)W_) && (py >= 0.f) && (py < (float)H_);
    const bool mask = valid && inb;
    const float sx = fmaxf(s5 * scale_x, 1.f);
    const float sy = fmaxf(s6 * scale_y, 1.f);
    if (j == 0) {
        float4* o = (float4*)(pp + (size_t)i * 8);
        o[0] = make_float4(px, py, 1.f / sx, 1.f / sy);
        o[1] = make_float4(wv, 0.5f * (sx + sy), 0.f, 0.f);
    }
    if (!mask) return;
    const float rx = 3.f * sx, ry = 3.f * sy;
    const int ymin = max(0, (int)floorf(py - ry));
    const int ymax = min(H_ - 1, (int)ceilf(py + ry));
    const int bmin = ymin >> 1, bmax = ymax >> 1;
    const int band = bmin + j;
    if (band > bmax) return;
    const int tmin = max(0, (int)floorf((px - rx - (float)(TW - 1)) * (1.f / TW)));
    const int tmax = min(NTX - 1, (int)ceilf((px + rx) * (1.f / TW)));
    const int b = i / N_, n = i - b * N_;
    for (int t = tmin; t <= tmax; ++t) {
        const int tile = (b * NYB + band) * NTX + t;
        const int slot = atomicAdd(&counts[tile], 1);
        if (slot < CAP) lists[(size_t)tile * CAP + slot] = (ushort_t)n;
    }
}

// ---------------------------------------------------------------------------
// Splat with MFMA phase B. Block = 16px x 2row tile; chunks of K=32.
// gw_t[px][k] bf16 (A operand), feats_t[ch][k] bf16 (B operand, staged via
// reg-transpose from global ftb). D[px][ch] = one mfma_16x16x32 per (mt,nt).
// ---------------------------------------------------------------------------
__global__ __launch_bounds__(256)
void splat_kernel(const float* __restrict__ pp, const ushort_t* __restrict__ lists,
                  const int* __restrict__ counts, const ushort_t* __restrict__ ftb,
                  float* __restrict__ out)
{
    __shared__ __align__(16) ushort_t feats_t[2][256 * FS];  // 2 x 20 KB
    __shared__ __align__(16) ushort_t gw_t[2][32 * FS];      // 2 x 2.5 KB

    const int tid = threadIdx.x;
    // center-first tile decode
    const int qb = blockIdx.x;
    const int b  = qb & 1;
    const int t_ = qb >> 1;
    const int yr = t_ / NTX, xr = t_ % NTX;
    const int yh = (yr + 1) >> 1;
    const int yb = (yr & 1) ? (16 - yh) : (16 + yh);
    const int xh = (xr + 1) >> 1;
    const int txi = (xr & 1) ? (5 - xh) : (5 + xh);
    const int bid = (b * NYB + yb) * NTX + txi;
    const int y0 = yb * 2, x0 = txi * TW;

    const int cnt = min(counts[bid], CAP);
    const ushort_t* mylist = lists + (size_t)bid * CAP;
    const int gs   = tid >> 5;            // phase A gaussian sub-slot (0..7)
    const int px32 = tid & 31;            // phase A pixel (row*16+x)
    const float fy = (float)(y0 + (px32 >> 4));
    const float fx = (float)(x0 + (px32 & 15));
    const int chg = tid >> 4;             // stage: ch group (0..15), 16 ch each
    const int qp  = tid & 15;             // stage: q pair (0..15)
    const int bN = b * N_;
    const int lane = tid & 63;
    const int wv_  = tid >> 6;
    const int quad = lane >> 4;
    const int ln15 = lane & 15;

    f32x4 acc[2][4];
#pragma unroll
    for (int mt = 0; mt < 2; ++mt)
#pragma unroll
        for (int nt = 0; nt < 4; ++nt) acc[mt][nt] = (f32x4){0.f, 0.f, 0.f, 0.f};
    float densp = 0.f, uncp = 0.f;

    uint4 ra0, ra1, rb0, rb1;             // staged 16ch x 2 rows
    const int nchunks = (cnt + 31) >> 5;

    if (cnt > 0) {
        const float4* pv = (const float4*)pp;
        {   // prefetch chunk 0 rows
            const int n0 = mylist[min(2 * qp, cnt - 1)];
            const int n1 = mylist[min(2 * qp + 1, cnt - 1)];
            const uint4* f0 = (const uint4*)(ftb + ((size_t)(bN + n0) << 8) + chg * 16);
            const uint4* f1 = (const uint4*)(ftb + ((size_t)(bN + n1) << 8) + chg * 16);
            ra0 = f0[0]; ra1 = f0[1];
            rb0 = f1[0]; rb1 = f1[1];
        }
        for (int c = 0; c < nchunks; ++c) {
            const int buf = c & 1;
            // ---- phase A: 4 gw per thread -> gw_t[buf] (bf16) ----
#pragma unroll
            for (int jj = 0; jj < 4; ++jj) {
                const int q = 8 * jj + gs;
                const int qi = c * 32 + q;
                const int n = mylist[min(qi, cnt - 1)];
                const float4 e0 = pv[(size_t)(bN + n) * 2 + 0];
                const float4 e1 = pv[(size_t)(bN + n) * 2 + 1];
                const float dyn = (fy - e0.y) * e0.w;
                const float dxn = (fx - e0.x) * e0.z;
                const float dist = dyn * dyn + dxn * dxn;
                float gv = 0.f;
                if (dist < 9.f) gv = __expf(-0.5f * dist) * e1.x;
                if (qi >= cnt) gv = 0.f;
                gw_t[buf][px32 * FS + q] = (ushort_t)f2bf(gv);
                densp += gv;
                uncp  += gv * e1.y;
            }
            // ---- stage: transpose regs -> feats_t[buf][ch][k] ----
            {
                uint* dst = (uint*)&feats_t[buf][0];
#pragma unroll
                for (int jj = 0; jj < 4; ++jj) {
                    const uint u0 = (&ra0.x)[jj], v0 = (&rb0.x)[jj];
                    const int ch = chg * 16 + 2 * jj;
                    dst[ch * (FS / 2) + qp]       = (u0 & 0xffffu) | (v0 << 16);
                    dst[(ch + 1) * (FS / 2) + qp] = (u0 >> 16) | (v0 & 0xffff0000u);
                }
#pragma unroll
                for (int jj = 0; jj < 4; ++jj) {
                    const uint u0 = (&ra1.x)[jj], v0 = (&rb1.x)[jj];
                    const int ch = chg * 16 + 8 + 2 * jj;
                    dst[ch * (FS / 2) + qp]       = (u0 & 0xffffu) | (v0 << 16);
                    dst[(ch + 1) * (FS / 2) + qp] = (u0 >> 16) | (v0 & 0xffff0000u);
                }
            }
            __syncthreads();
            // ---- prefetch chunk c+1 rows (overlaps phase B) ----
            if (c + 1 < nchunks) {
                const int q0 = (c + 1) * 32 + 2 * qp;
                const int n0 = mylist[min(q0, cnt - 1)];
                const int n1 = mylist[min(q0 + 1, cnt - 1)];
                const uint4* f0 = (const uint4*)(ftb + ((size_t)(bN + n0) << 8) + chg * 16);
                const uint4* f1 = (const uint4*)(ftb + ((size_t)(bN + n1) << 8) + chg * 16);
                ra0 = f0[0]; ra1 = f0[1];
                rb0 = f1[0]; rb1 = f1[1];
            }
            // ---- phase B: 8 MFMA per wave ----
            bf16x8 af[2];
#pragma unroll
            for (int mt = 0; mt < 2; ++mt)
                af[mt] = *(const bf16x8*)&gw_t[buf][(mt * 16 + ln15) * FS + quad * 8];
#pragma unroll
            for (int nt = 0; nt < 4; ++nt) {
                const int ch0 = wv_ * 64 + nt * 16;
                const bf16x8 bf = *(const bf16x8*)&feats_t[buf][(ch0 + ln15) * FS + quad * 8];
                acc[0][nt] = __builtin_amdgcn_mfma_f32_16x16x32_bf16(af[0], bf, acc[0][nt], 0, 0, 0);
                acc[1][nt] = __builtin_amdgcn_mfma_f32_16x16x32_bf16(af[1], bf, acc[1][nt], 0, 0, 0);
            }
        }
    }

    // ---- density / uncertainty reduction over 8 gs-groups ----
    __syncthreads();
    float* red_d = (float*)&feats_t[0][0];   // 8 x 36
    float* red_u = red_d + 8 * 36;
    red_d[gs * 36 + px32] = densp;
    red_u[gs * 36 + px32] = uncp;
    __syncthreads();
    for (int s = 4; s > 0; s >>= 1) {
        if (gs < s) {
            red_d[gs * 36 + px32] += red_d[(gs + s) * 36 + px32];
            red_u[gs * 36 + px32] += red_u[(gs + s) * 36 + px32];
        }
        __syncthreads();
    }

    if (tid < 32) {
        const int yy = y0 + (tid >> 4), xx = x0 + (tid & 15);
        const size_t pix = ((size_t)b * H_ + yy) * W_ + xx;
        float* unc_o = out + (size_t)B_ * C_ * H_ * W_;
        float* den_o = unc_o + (size_t)B_ * H_ * W_;
        const float d = fmaxf(red_d[tid], 1e-6f);
        unc_o[pix] = red_u[tid] / d;
        den_o[pix] = d;
    }

    // ---- feature stores: lane = ch (ln15), 4 consecutive x per acc ----
#pragma unroll
    for (int mt = 0; mt < 2; ++mt) {
        const int pxb = mt * 16 + quad * 4;
        float rinv[4];
#pragma unroll
        for (int r = 0; r < 4; ++r)
            rinv[r] = 1.f / fmaxf(red_d[pxb + r], 1e-6f);
        const int yy = y0 + mt;
#pragma unroll
        for (int nt = 0; nt < 4; ++nt) {
            const int ch = wv_ * 64 + nt * 16 + ln15;
            float4 v;
            v.x = acc[mt][nt][0] * rinv[0];
            v.y = acc[mt][nt][1] * rinv[1];
            v.z = acc[mt][nt][2] * rinv[2];
            v.w = acc[mt][nt][3] * rinv[3];
            *(float4*)(out + (((size_t)b * C_ + ch) * H_ + yy) * W_
                       + x0 + quad * 4) = v;
        }
    }
}

// ---------------------------------------------------------------------------
extern "C" void kernel_launch(void* const* d_in, const int* in_sizes, int n_in,
                              void* d_out, int out_size, void* d_ws, size_t ws_size,
                              hipStream_t stream)
{
    const float* g    = (const float*)d_in[0];
    const float* intr = (const float*)d_in[1];
    const float* w1   = (const float*)d_in[2];
    const float* b1   = (const float*)d_in[3];
    const float* w2   = (const float*)d_in[4];
    const float* b2   = (const float*)d_in[5];
    const float* w3   = (const float*)d_in[6];
    const float* b3   = (const float*)d_in[7];
    const float* fw1  = (const float*)d_in[8];
    const float* fb1  = (const float*)d_in[9];
    const float* fw2  = (const float*)d_in[10];
    const float* fb2  = (const float*)d_in[11];

    char* base = (char*)d_ws;
    const int rows = B_ * N_;                                // 4096
    ushort_t* ftb = (ushort_t*)base;                         // 2 MB bf16 [row][ch]
    float* pp     = (float*)(base + (size_t)rows * C_ * 2);  // 128 KB
    int*   counts = (int*)(pp + (size_t)8 * rows);           // 704 ints
    ushort_t* lists = (ushort_t*)(counts + NTILES2);         // 1.4 MB
    short* wt3    = (short*)(lists + (size_t)NTILES2 * CAP);
    short* wt4    = wt3 + 128 * 256;
    short* wt5    = wt4 + 256 * 256;

    prep_kernel<<<dim3(256), dim3(256), 0, stream>>>(w3, fw1, fw2, wt3, wt4, wt5, counts);
    pb_mlp_kernel<<<dim3(512), dim3(512), 0, stream>>>(
        g, intr, w1, b1, w2, b2, wt3, b3, wt4, fb1, wt5, fb2, ftb, pp, counts, lists);
    splat_kernel<<<dim3(NTILES2), dim3(256), 0, stream>>>(pp, lists, counts, ftb, (float*)d_out);
}